// Round 20
// baseline (450.997 us; speedup 1.0000x reference)
//
#include <hip/hip_runtime.h>
#include <stdint.h>

#define B_   64
#define S_   197
#define D_   768
#define H_   12
#define F_   3072
#define BS_  (B_ * S_)   // 12608

typedef __attribute__((ext_vector_type(8))) short short8;
typedef __attribute__((ext_vector_type(4))) float f32x4;

__device__ __forceinline__ float bf2f(unsigned short h) {
    union { unsigned int u; float f; } v; v.u = ((unsigned int)h) << 16; return v.f;
}
__device__ __forceinline__ unsigned short f2bf(float f) {
    union { float f; unsigned int u; } v; v.f = f;
    unsigned int r = v.u + 0x7FFFu + ((v.u >> 16) & 1u);
    return (unsigned short)(r >> 16);
}

__device__ __forceinline__ void g2l16(const void* g, void* l) {
    __builtin_amdgcn_global_load_lds(
        (const __attribute__((address_space(1))) unsigned int*)g,
        (__attribute__((address_space(3))) unsigned int*)l, 16, 0, 0);
}

// exact-enough GELU: A&S 7.1.26 erf (max abs err 1.5e-7)
__device__ __forceinline__ float gelu_f(float c) {
    float z = fabsf(c) * 0.70710678118f;
    float t = __builtin_amdgcn_rcpf(1.f + 0.3275911f * z);
    float p = ((((1.061405429f * t - 1.453152027f) * t + 1.421413741f) * t
               - 0.284496736f) * t + 0.254829592f) * t;
    float erfv = 1.f - p * __expf(-z * z);
    erfv = c < 0.f ? -erfv : erfv;
    return 0.5f * c * (1.f + erfv);
}

// ---------------- fused prep: weight transpose + bias concat + LN1 ----------------
__global__ __launch_bounds__(256)
void prep_kernel(const float* __restrict__ Wq, const float* __restrict__ Wk,
                 const float* __restrict__ Wv, const float* __restrict__ Wo,
                 const float* __restrict__ W1, const float* __restrict__ W2,
                 const float* __restrict__ bq, const float* __restrict__ bk,
                 const float* __restrict__ bv,
                 const float* __restrict__ x, const float* __restrict__ ln1w,
                 const float* __restrict__ ln1b,
                 unsigned short* __restrict__ wqkvT, unsigned short* __restrict__ woT,
                 unsigned short* __restrict__ w1T, unsigned short* __restrict__ w2T,
                 float* __restrict__ bcat, unsigned short* __restrict__ hbuf) {
    int blk = blockIdx.x;
    int tid = threadIdx.x;
    if (blk >= 6913) {
        // ---- LayerNorm1 rows ----
        int row = blk - 6913; size_t base = (size_t)row * 768;
        float v0 = x[base + tid], v1 = x[base + tid + 256], v2 = x[base + tid + 512];
        float s1 = v0 + v1 + v2;
        float s2 = v0 * v0 + v1 * v1 + v2 * v2;
#pragma unroll
        for (int off = 32; off > 0; off >>= 1) { s1 += __shfl_xor(s1, off); s2 += __shfl_xor(s2, off); }
        __shared__ float sa[4], sb[4];
        int w4 = tid >> 6;
        if ((tid & 63) == 0) { sa[w4] = s1; sb[w4] = s2; }
        __syncthreads();
        s1 = sa[0] + sa[1] + sa[2] + sa[3];
        s2 = sb[0] + sb[1] + sb[2] + sb[3];
        float mean = s1 * (1.f / 768.f);
        float var  = s2 * (1.f / 768.f) - mean * mean;
        float rstd = rsqrtf(var + 1e-6f);
        hbuf[base + tid]       = f2bf((v0 - mean) * rstd * ln1w[tid]       + ln1b[tid]);
        hbuf[base + tid + 256] = f2bf((v1 - mean) * rstd * ln1w[tid + 256] + ln1b[tid + 256]);
        hbuf[base + tid + 512] = f2bf((v2 - mean) * rstd * ln1w[tid + 512] + ln1b[tid + 512]);
        return;
    }
    if (blk == 6912) {
        for (int i = tid; i < 2304; i += 256)
            bcat[i] = i < 768 ? bq[i] : (i < 1536 ? bk[i - 768] : bv[i - 1536]);
        return;
    }
    // ---- weight transpose tiles ----
    int tx = tid & 31, ty = tid >> 5;
    const float* W; unsigned short* Wt; int K, N, rel, nx;
    if (blk < 2304) {
        int m = blk / 576; rel = blk - m * 576; K = 768; N = 768; nx = 24;
        W  = m == 0 ? Wq : m == 1 ? Wk : m == 2 ? Wv : Wo;
        Wt = m < 3 ? wqkvT + (size_t)m * 768 * 768 : woT;
    } else if (blk < 4608) {
        rel = blk - 2304; K = 768; N = 3072; nx = 96; W = W1; Wt = w1T;
    } else {
        rel = blk - 4608; K = 3072; N = 768; nx = 24; W = W2; Wt = w2T;
    }
    int n0 = (rel % nx) * 32, k0 = (rel / nx) * 32;
    __shared__ float t[32][33];
#pragma unroll
    for (int i = ty; i < 32; i += 8) t[i][tx] = W[(size_t)(k0 + i) * N + n0 + tx];
    __syncthreads();
#pragma unroll
    for (int i = ty; i < 32; i += 8) Wt[(size_t)(n0 + i) * K + k0 + tx] = f2bf(t[tx][i]);
}

// ---------------- LayerNorm: f32 in -> bf16 out (used for LN2) ----------------
__global__ __launch_bounds__(256)
void ln_kernel(const float* __restrict__ x, const float* __restrict__ w,
               const float* __restrict__ b, unsigned short* __restrict__ out) {
    int row = blockIdx.x; size_t base = (size_t)row * 768;
    int tid = threadIdx.x;
    float v0 = x[base + tid], v1 = x[base + tid + 256], v2 = x[base + tid + 512];
    float s1 = v0 + v1 + v2;
    float s2 = v0 * v0 + v1 * v1 + v2 * v2;
#pragma unroll
    for (int off = 32; off > 0; off >>= 1) { s1 += __shfl_xor(s1, off); s2 += __shfl_xor(s2, off); }
    __shared__ float sa[4], sb[4];
    int w4 = tid >> 6;
    if ((tid & 63) == 0) { sa[w4] = s1; sb[w4] = s2; }
    __syncthreads();
    s1 = sa[0] + sa[1] + sa[2] + sa[3];
    s2 = sb[0] + sb[1] + sb[2] + sb[3];
    float mean = s1 * (1.f / 768.f);
    float var  = s2 * (1.f / 768.f) - mean * mean;
    float rstd = rsqrtf(var + 1e-6f);
    out[base + tid]       = f2bf((v0 - mean) * rstd * w[tid]       + b[tid]);
    out[base + tid + 256] = f2bf((v1 - mean) * rstd * w[tid + 256] + b[tid + 256]);
    out[base + tid + 512] = f2bf((v2 - mean) * rstd * w[tid + 512] + b[tid + 512]);
}

// ---------------- GEMM: phase template, ring-3, counted vmcnt ------
// GEOM 0: 512 thr / 8 waves (2Mx4N), 256x256 tile, wave 128x64, 2 phases/tile, LDS 96KB.
// GEOM 1: 256 thr / 4 waves (2Mx2N), 128x128 tile, wave 64x64, 1 phase/tile, LDS 48KB.
// GEOM 2: 256 thr / 4 waves (1Mx4N),  64x128 tile, wave 64x32, 1 phase/tile, LDS 36KB.
// Ring-3 LDS: tile t reads ring t%3, stages tile t+2 into (t+2)%3; boundary is
// {vmcnt(SC) -> s_barrier -> reads} where SC = stage-calls/tile (4 or 3): tile kt+1's
// calls stay in flight — never drains until the tail. Phase = {ds_read subtile ->
// stage calls -> s_barrier -> lgkmcnt(0)+sched_barrier(0) -> setprio(1) -> MFMA ->
// setprio(0) -> s_barrier}. Swizzle + serpentine + m204 as verified (0 conflicts).
// Geometry choice is grid-size-driven (R18/R19 A/B: finer tiles win at these shapes —
// tail quantization on 256 CUs + more co-resident blocks/CU).
template<int MODE, int GEOM>
__global__ __launch_bounds__(GEOM == 0 ? 512 : 256)
void gemm8ph(const unsigned short* __restrict__ A, const unsigned short* __restrict__ Bt,
             const float* __restrict__ bias, const float* __restrict__ resid,
             void* __restrict__ out, int M, int N, int K, int NSUP) {
    constexpr int BK  = 32;
    constexpr int BM  = GEOM == 0 ? 256 : (GEOM == 1 ? 128 : 64);
    constexpr int BN  = GEOM == 0 ? 256 : 128;
    constexpr int NTH = GEOM == 0 ? 512 : 256;
    constexpr int WGN = GEOM == 1 ? 2 : 4;
    constexpr int WM  = GEOM == 0 ? 128 : 64;
    constexpr int WN  = GEOM == 2 ? 32 : 64;
    constexpr int MT  = WM / 16, NT = WN / 16;
    constexpr int PH  = MT / 4;
    constexpr int RPC = NTH / 4;                       // rows per stage call
    constexpr int SC  = BM / RPC + BN / RPC;           // stage calls per K-tile (4 or 3)

    __shared__ unsigned short As[3][BM * BK];
    __shared__ unsigned short Bs[3][BN * BK];
    const int tid = threadIdx.x;
    const int l = tid & 63, wid = tid >> 6;
    const int lr = l & 15, lg = l >> 4;
    const int wr = wid / WGN, wc = wid % WGN;

    const int nN = gridDim.x, nM = gridDim.y;
    const int nTot = nN * nM;
    const int orig = blockIdx.x + nN * blockIdx.y;
    const int q8 = nTot >> 3, r8 = nTot & 7;
    const int xcd = orig & 7, idx = orig >> 3;
    const int rank = (xcd < r8 ? xcd * (q8 + 1) : r8 * (q8 + 1) + (xcd - r8) * q8) + idx;
    const int fullg = nM * NSUP;
    const int sup = rank / fullg;
    const int rem = rank - sup * fullg;
    const int n0s = sup * NSUP;
    int wsup = nN - n0s; if (wsup > NSUP) wsup = NSUP;
    const int mloc = rem / wsup;
    const int nloc = rem - mloc * wsup;
    const int bm0 = mloc * BM;
    const int bn0 = (n0s + nloc) * BN;

    const int srow = wid * (RPC / 4) + (l >> 2);
    const int slb  = (l & 3) ^ ((l >> 3) & 3);
    auto stageHalf = [&](int ring, int kt, int half) {
        const int k0 = kt * BK;
        if (half == 0) {
#pragma unroll
            for (int c = 0; c < BM / RPC; ++c) {
                int gr = bm0 + c * RPC + srow; gr = gr < M ? gr : M - 1;
                g2l16(A + (size_t)gr * K + k0 + slb * 8, &As[ring][(c * RPC + wid * (RPC / 4)) * BK]);
            }
        } else {
#pragma unroll
            for (int c = 0; c < BN / RPC; ++c) {
                int gr = bn0 + c * RPC + srow;
                g2l16(Bt + (size_t)gr * K + k0 + slb * 8, &Bs[ring][(c * RPC + wid * (RPC / 4)) * BK]);
            }
        }
    };

    f32x4 acc[MT][NT];
#pragma unroll
    for (int i = 0; i < MT; ++i)
#pragma unroll
        for (int j = 0; j < NT; ++j) acc[i][j] = (f32x4){0.f, 0.f, 0.f, 0.f};

    const int NK = K / BK;
    stageHalf(0, 0, 0); stageHalf(0, 0, 1);
    stageHalf(1, 1, 0); stageHalf(1, 1, 1);

    const int rxor = (lr >> 1) & 3;
    int ring = 0;
    for (int kt = 0; kt < NK; ++kt) {
        if (kt + 1 < NK) {
            if constexpr (SC == 4) { asm volatile("s_waitcnt vmcnt(4)" ::: "memory"); }
            else                   { asm volatile("s_waitcnt vmcnt(3)" ::: "memory"); }
        } else {
            asm volatile("s_waitcnt vmcnt(0)" ::: "memory");
        }
        __builtin_amdgcn_s_barrier();
        __builtin_amdgcn_sched_barrier(0);
        const unsigned short* Ab = &As[ring][0];
        const unsigned short* Bb = &Bs[ring][0];
        const int rnext = ring >= 1 ? ring - 1 : 2;
        const bool st = (kt + 2 < NK);

        short8 bfr[NT];
#pragma unroll
        for (int nt = 0; nt < NT; ++nt)
            bfr[nt] = *(const short8*)&Bb[(wc * WN + nt * 16 + lr) * BK + ((lg ^ rxor) * 8)];
#pragma unroll
        for (int ph = 0; ph < PH; ++ph) {
            short8 af[4];
#pragma unroll
            for (int mt = 0; mt < 4; ++mt)
                af[mt] = *(const short8*)&Ab[(wr * WM + (ph * 4 + mt) * 16 + lr) * BK + ((lg ^ rxor) * 8)];
            if (st) stageHalf(rnext, kt + 2, ph);
            if (PH == 1 && st) stageHalf(rnext, kt + 2, 1);
            __builtin_amdgcn_s_barrier();
            asm volatile("s_waitcnt lgkmcnt(0)" ::: "memory");
            __builtin_amdgcn_sched_barrier(0);
            __builtin_amdgcn_s_setprio(1);
#pragma unroll
            for (int mt = 0; mt < 4; ++mt)
#pragma unroll
                for (int nt = 0; nt < NT; ++nt)
                    acc[ph * 4 + mt][nt] = __builtin_amdgcn_mfma_f32_16x16x32_bf16(
                        af[mt], bfr[nt], acc[ph * 4 + mt][nt], 0, 0, 0);
            __builtin_amdgcn_s_setprio(0);
            __builtin_amdgcn_s_barrier();
        }
        ring = ring < 2 ? ring + 1 : 0;
    }

#pragma unroll
    for (int mt = 0; mt < MT; ++mt)
#pragma unroll
        for (int nt = 0; nt < NT; ++nt)
#pragma unroll
            for (int r = 0; r < 4; ++r) {
                int gm = bm0 + wr * WM + mt * 16 + lg * 4 + r;
                int gn = bn0 + wc * WN + nt * 16 + lr;
                if (gm < M) {
                    float c = acc[mt][nt][r] + bias[gn];
                    if (MODE == 0) {
                        if (gn < 768) c *= 0.125f;
                        ((unsigned short*)out)[(size_t)gm * N + gn] = f2bf(c);
                    } else if (MODE == 1) {
                        ((float*)out)[(size_t)gm * N + gn] = c + resid[(size_t)gm * N + gn];
                    } else {
                        ((unsigned short*)out)[(size_t)gm * N + gn] = f2bf(gelu_f(c));
                    }
                }
            }
}

// ---------------- MFMA attention: one block per (b,h), 4 waves ----------------
__global__ __launch_bounds__(256)
void attn_mfma(const unsigned short* __restrict__ qkv, const int* __restrict__ mask,
               unsigned short* __restrict__ ctx) {
    __shared__ unsigned short Ks[208 * 64];
    __shared__ unsigned short Vt[64 * 256];
    __shared__ unsigned short Psl[4][16 * 40];
    __shared__ float maskadj[224];
    const int bh = blockIdx.x, b = bh / 12, h = bh - b * 12;
    const int tid = threadIdx.x, l = tid & 63, w = tid >> 6;
    const int lr = l & 15, lg = l >> 4;
    const unsigned short* Qg = qkv + (size_t)b * 197 * 2304 + h * 64;
    const unsigned short* Kg = Qg + 768;
    const unsigned short* Vg = Qg + 1536;

    if (tid < 224)
        maskadj[tid] = tid < 197 ? -10000.f * (1.f - (float)mask[b * 197 + tid]) : -1e30f;

    for (int c = w; c < 26; c += 4) {
        int row = c * 8 + (l >> 3);
        int rc = row < 197 ? row : 196;
        int blk = (l & 7) ^ (row & 7);
        g2l16(Kg + (size_t)rc * 2304 + blk * 8, &Ks[c * 8 * 64]);
    }
    {
        int jj = tid >> 3, db = tid & 7;
#pragma unroll
        for (int it = 0; it < 7; ++it) {
            int j = it * 32 + jj;
            short8 v = (short8){0, 0, 0, 0, 0, 0, 0, 0};
            if (j < 197) v = *(const short8*)(Vg + (size_t)j * 2304 + db * 8);
#pragma unroll
            for (int e = 0; e < 8; ++e) {
                int d = db * 8 + e;
                Vt[d * 256 + (((j >> 3) ^ (d & 7)) * 8) + (j & 7)] = (unsigned short)v[e];
            }
        }
    }
    __syncthreads();

    for (int t = w; t < 13; t += 4) {
        const int q0 = t * 16;
        int qr = q0 + lr; qr = qr < 197 ? qr : 196;
        const short8 qf0 = *(const short8*)(Qg + (size_t)qr * 2304 + lg * 8);
        const short8 qf1 = *(const short8*)(Qg + (size_t)qr * 2304 + 32 + lg * 8);

        f32x4 sc[13];
#pragma unroll
        for (int kt = 0; kt < 13; ++kt) {
            const int krow = kt * 16 + lr;
            const short8 kf0 = *(const short8*)&Ks[krow * 64 + ((lg ^ (lr & 7)) * 8)];
            const short8 kf1 = *(const short8*)&Ks[krow * 64 + (((4 + lg) ^ (lr & 7)) * 8)];
            f32x4 a = (f32x4){0.f, 0.f, 0.f, 0.f};
            a = __builtin_amdgcn_mfma_f32_16x16x32_bf16(qf0, kf0, a, 0, 0, 0);
            a = __builtin_amdgcn_mfma_f32_16x16x32_bf16(qf1, kf1, a, 0, 0, 0);
            sc[kt] = a;
        }
        float mx[4] = {-1e30f, -1e30f, -1e30f, -1e30f};
#pragma unroll
        for (int kt = 0; kt < 13; ++kt) {
            float ma = maskadj[kt * 16 + lr];
#pragma unroll
            for (int r = 0; r < 4; ++r) {
                sc[kt][r] += ma;
                mx[r] = fmaxf(mx[r], sc[kt][r]);
            }
        }
#pragma unroll
        for (int r = 0; r < 4; ++r) {
            mx[r] = fmaxf(mx[r], __shfl_xor(mx[r], 1));
            mx[r] = fmaxf(mx[r], __shfl_xor(mx[r], 2));
            mx[r] = fmaxf(mx[r], __shfl_xor(mx[r], 4));
            mx[r] = fmaxf(mx[r], __shfl_xor(mx[r], 8));
        }
        float sm[4] = {0.f, 0.f, 0.f, 0.f};
#pragma unroll
        for (int kt = 0; kt < 13; ++kt)
#pragma unroll
            for (int r = 0; r < 4; ++r) {
                float p = __expf(sc[kt][r] - mx[r]);
                sc[kt][r] = p;
                sm[r] += p;
            }
#pragma unroll
        for (int r = 0; r < 4; ++r) {
            sm[r] += __shfl_xor(sm[r], 1);
            sm[r] += __shfl_xor(sm[r], 2);
            sm[r] += __shfl_xor(sm[r], 4);
            sm[r] += __shfl_xor(sm[r], 8);
            sm[r] = 1.f / sm[r];
        }
        f32x4 ao[4];
#pragma unroll
        for (int dt = 0; dt < 4; ++dt) ao[dt] = (f32x4){0.f, 0.f, 0.f, 0.f};
        unsigned short* Pw = &Psl[w][0];
#pragma unroll
        for (int ks = 0; ks < 7; ++ks) {
#pragma unroll
            for (int tl = 0; tl < 2; ++tl) {
                const int kt = ks * 2 + tl;
#pragma unroll
                for (int r = 0; r < 4; ++r) {
                    unsigned short pv = 0;
                    if (kt < 13) pv = f2bf(sc[kt][r] * sm[r]);
                    Pw[(lg * 4 + r) * 40 + tl * 16 + lr] = pv;
                }
            }
            const short8 pf = *(const short8*)&Pw[lr * 40 + lg * 8];
#pragma unroll
            for (int dt = 0; dt < 4; ++dt) {
                const int drow = dt * 16 + lr;
                const short8 vf = *(const short8*)&Vt[drow * 256 + (((4 * ks + lg) ^ (lr & 7)) * 8)];
                ao[dt] = __builtin_amdgcn_mfma_f32_16x16x32_bf16(vf, pf, ao[dt], 0, 0, 0);
            }
        }
        const int q = q0 + lr;
        if (q < 197) {
            unsigned short* crow = ctx + ((size_t)b * 197 + q) * 768 + h * 64;
#pragma unroll
            for (int dt = 0; dt < 4; ++dt) {
                union { unsigned short u[4]; uint2 v; } pk;
#pragma unroll
                for (int r = 0; r < 4; ++r) pk.u[r] = f2bf(ao[dt][r]);
                *(uint2*)(crow + dt * 16 + lg * 4) = pk.v;
            }
        }
    }
}

extern "C" void kernel_launch(void* const* d_in, const int* in_sizes, int n_in,
                              void* d_out, int out_size, void* d_ws, size_t ws_size,
                              hipStream_t stream) {
    const float* x    = (const float*)d_in[0];
    const float* Wq   = (const float*)d_in[1];
    const float* bq   = (const float*)d_in[2];
    const float* Wk   = (const float*)d_in[3];
    const float* bk   = (const float*)d_in[4];
    const float* Wv   = (const float*)d_in[5];
    const float* bv   = (const float*)d_in[6];
    const float* Wo   = (const float*)d_in[7];
    const float* bo   = (const float*)d_in[8];
    const float* ln1w = (const float*)d_in[9];
    const float* ln1b = (const float*)d_in[10];
    const float* W1   = (const float*)d_in[11];
    const float* b1   = (const float*)d_in[12];
    const float* W2   = (const float*)d_in[13];
    const float* b2   = (const float*)d_in[14];
    const float* ln2w = (const float*)d_in[15];
    const float* ln2b = (const float*)d_in[16];
    const int*   mask = (const int*)d_in[17];

    size_t off = 0;
    auto nxt = [&](size_t bytes) -> void* {
        void* r = (char*)d_ws + off; off += (bytes + 255) & ~(size_t)255; return r;
    };
    unsigned short* hbuf  = (unsigned short*)nxt((size_t)BS_ * 768 * 2);
    unsigned short* qkvg  = (unsigned short*)nxt((size_t)BS_ * 3072 * 2);  // QKV (2304), reused for FFN1 out (3072)
    unsigned short* wqkvT = (unsigned short*)nxt((size_t)2304 * 768 * 2);
    unsigned short* woT   = (unsigned short*)nxt((size_t)768 * 768 * 2);
    unsigned short* w1T   = (unsigned short*)nxt((size_t)3072 * 768 * 2);
    unsigned short* w2T   = (unsigned short*)nxt((size_t)768 * 3072 * 2);
    float*          bcat  = (float*)nxt(2304 * 4);
    unsigned short* ctx   = (unsigned short*)nxt((size_t)BS_ * 768 * 2);
    (void)ws_size; (void)in_sizes; (void)n_in; (void)out_size;

    // prep: weight transposes + bias concat + LN1 overlapped in one dispatch
    prep_kernel<<<6913 + BS_, 256, 0, stream>>>(Wq, Wk, Wv, Wo, W1, W2, bq, bk, bv,
                                                x, ln1w, ln1b,
                                                wqkvT, woT, w1T, w2T, bcat, hbuf);
    // QKV: GEOM1, 1782 blocks (R18-verified)
    gemm8ph<0, 1><<<dim3(18, 99), 256, 0, stream>>>(hbuf, wqkvT, bcat, nullptr, qkvg, BS_, 2304, 768, 9);
    attn_mfma<<<768, 256, 0, stream>>>(qkvg, mask, ctx);
    // O-proj: GEOM2 (64x128) -> 1182 blocks (was 594: 2.32-round tail), NSUP=6 (whole B resident)
    gemm8ph<1, 2><<<dim3(6, 197), 256, 0, stream>>>(ctx, woT, bo, x, d_out, BS_, 768, 768, 6);
    ln_kernel<<<BS_, 256, 0, stream>>>((const float*)d_out, ln2w, ln2b, hbuf);
    // FFN1: GEOM1, 2376 blocks (R19-verified: 154.5 -> 130.8)
    gemm8ph<2, 1><<<dim3(24, 99), 256, 0, stream>>>(hbuf, w1T, b1, nullptr, qkvg, BS_, 3072, 768, 12);
    // FFN2: GEOM2 (64x128), K=3072 -> 1182 blocks, NSUP=3 (B-super 2.36MB)
    gemm8ph<1, 2><<<dim3(6, 197), 256, 0, stream>>>(qkvg, w2T, b2, (const float*)d_out, d_out, BS_, 768, 3072, 3);
}

// Round 21
// 414.849 us; speedup vs baseline: 1.0871x; 1.0871x over previous
//
#include <hip/hip_runtime.h>
#include <stdint.h>

#define B_   64
#define S_   197
#define D_   768
#define H_   12
#define F_   3072
#define BS_  (B_ * S_)   // 12608

typedef __attribute__((ext_vector_type(8))) short short8;
typedef __attribute__((ext_vector_type(4))) float f32x4;

__device__ __forceinline__ float bf2f(unsigned short h) {
    union { unsigned int u; float f; } v; v.u = ((unsigned int)h) << 16; return v.f;
}
__device__ __forceinline__ unsigned short f2bf(float f) {
    union { float f; unsigned int u; } v; v.f = f;
    unsigned int r = v.u + 0x7FFFu + ((v.u >> 16) & 1u);
    return (unsigned short)(r >> 16);
}

__device__ __forceinline__ void g2l16(const void* g, void* l) {
    __builtin_amdgcn_global_load_lds(
        (const __attribute__((address_space(1))) unsigned int*)g,
        (__attribute__((address_space(3))) unsigned int*)l, 16, 0, 0);
}

// exact-enough GELU: A&S 7.1.26 erf (max abs err 1.5e-7)
__device__ __forceinline__ float gelu_f(float c) {
    float z = fabsf(c) * 0.70710678118f;
    float t = __builtin_amdgcn_rcpf(1.f + 0.3275911f * z);
    float p = ((((1.061405429f * t - 1.453152027f) * t + 1.421413741f) * t
               - 0.284496736f) * t + 0.254829592f) * t;
    float erfv = 1.f - p * __expf(-z * z);
    erfv = c < 0.f ? -erfv : erfv;
    return 0.5f * c * (1.f + erfv);
}

// ---------------- fused prep: weight transpose + bias concat + LN1 ----------------
__global__ __launch_bounds__(256)
void prep_kernel(const float* __restrict__ Wq, const float* __restrict__ Wk,
                 const float* __restrict__ Wv, const float* __restrict__ Wo,
                 const float* __restrict__ W1, const float* __restrict__ W2,
                 const float* __restrict__ bq, const float* __restrict__ bk,
                 const float* __restrict__ bv,
                 const float* __restrict__ x, const float* __restrict__ ln1w,
                 const float* __restrict__ ln1b,
                 unsigned short* __restrict__ wqkvT, unsigned short* __restrict__ woT,
                 unsigned short* __restrict__ w1T, unsigned short* __restrict__ w2T,
                 float* __restrict__ bcat, unsigned short* __restrict__ hbuf) {
    int blk = blockIdx.x;
    int tid = threadIdx.x;
    if (blk >= 6913) {
        // ---- LayerNorm1 rows ----
        int row = blk - 6913; size_t base = (size_t)row * 768;
        float v0 = x[base + tid], v1 = x[base + tid + 256], v2 = x[base + tid + 512];
        float s1 = v0 + v1 + v2;
        float s2 = v0 * v0 + v1 * v1 + v2 * v2;
#pragma unroll
        for (int off = 32; off > 0; off >>= 1) { s1 += __shfl_xor(s1, off); s2 += __shfl_xor(s2, off); }
        __shared__ float sa[4], sb[4];
        int w4 = tid >> 6;
        if ((tid & 63) == 0) { sa[w4] = s1; sb[w4] = s2; }
        __syncthreads();
        s1 = sa[0] + sa[1] + sa[2] + sa[3];
        s2 = sb[0] + sb[1] + sb[2] + sb[3];
        float mean = s1 * (1.f / 768.f);
        float var  = s2 * (1.f / 768.f) - mean * mean;
        float rstd = rsqrtf(var + 1e-6f);
        hbuf[base + tid]       = f2bf((v0 - mean) * rstd * ln1w[tid]       + ln1b[tid]);
        hbuf[base + tid + 256] = f2bf((v1 - mean) * rstd * ln1w[tid + 256] + ln1b[tid + 256]);
        hbuf[base + tid + 512] = f2bf((v2 - mean) * rstd * ln1w[tid + 512] + ln1b[tid + 512]);
        return;
    }
    if (blk == 6912) {
        for (int i = tid; i < 2304; i += 256)
            bcat[i] = i < 768 ? bq[i] : (i < 1536 ? bk[i - 768] : bv[i - 1536]);
        return;
    }
    // ---- weight transpose tiles ----
    int tx = tid & 31, ty = tid >> 5;
    const float* W; unsigned short* Wt; int K, N, rel, nx;
    if (blk < 2304) {
        int m = blk / 576; rel = blk - m * 576; K = 768; N = 768; nx = 24;
        W  = m == 0 ? Wq : m == 1 ? Wk : m == 2 ? Wv : Wo;
        Wt = m < 3 ? wqkvT + (size_t)m * 768 * 768 : woT;
    } else if (blk < 4608) {
        rel = blk - 2304; K = 768; N = 3072; nx = 96; W = W1; Wt = w1T;
    } else {
        rel = blk - 4608; K = 3072; N = 768; nx = 24; W = W2; Wt = w2T;
    }
    int n0 = (rel % nx) * 32, k0 = (rel / nx) * 32;
    __shared__ float t[32][33];
#pragma unroll
    for (int i = ty; i < 32; i += 8) t[i][tx] = W[(size_t)(k0 + i) * N + n0 + tx];
    __syncthreads();
#pragma unroll
    for (int i = ty; i < 32; i += 8) Wt[(size_t)(n0 + i) * K + k0 + tx] = f2bf(t[tx][i]);
}

// ---------------- LayerNorm: f32 in -> bf16 out (used for LN2) ----------------
__global__ __launch_bounds__(256)
void ln_kernel(const float* __restrict__ x, const float* __restrict__ w,
               const float* __restrict__ b, unsigned short* __restrict__ out) {
    int row = blockIdx.x; size_t base = (size_t)row * 768;
    int tid = threadIdx.x;
    float v0 = x[base + tid], v1 = x[base + tid + 256], v2 = x[base + tid + 512];
    float s1 = v0 + v1 + v2;
    float s2 = v0 * v0 + v1 * v1 + v2 * v2;
#pragma unroll
    for (int off = 32; off > 0; off >>= 1) { s1 += __shfl_xor(s1, off); s2 += __shfl_xor(s2, off); }
    __shared__ float sa[4], sb[4];
    int w4 = tid >> 6;
    if ((tid & 63) == 0) { sa[w4] = s1; sb[w4] = s2; }
    __syncthreads();
    s1 = sa[0] + sa[1] + sa[2] + sa[3];
    s2 = sb[0] + sb[1] + sb[2] + sb[3];
    float mean = s1 * (1.f / 768.f);
    float var  = s2 * (1.f / 768.f) - mean * mean;
    float rstd = rsqrtf(var + 1e-6f);
    out[base + tid]       = f2bf((v0 - mean) * rstd * w[tid]       + b[tid]);
    out[base + tid + 256] = f2bf((v1 - mean) * rstd * w[tid + 256] + b[tid + 256]);
    out[base + tid + 512] = f2bf((v2 - mean) * rstd * w[tid + 512] + b[tid + 512]);
}

// ---------------- GEMM (session-best R19 config): phase template, ring-3, counted vmcnt --
// GEOM 1: 256 thr / 4 waves (2Mx2N), 128x128 tile, wave 64x64, 1 phase/tile, LDS 48KB.
// (GEOM0 256# too coarse: 1 block/CU + tail waste, R13-R18 ~154us; GEOM2 64x128 too
// fine: 8-MFMA phases lose to sync overhead, R20 139us. 128# is the measured optimum:
// 16 MFMA/phase, 2 blocks/CU, fine tail -> QKV ~115, FFN1 130.8, R19 total 416.6us.)
// Ring-3 LDS: tile t reads ring t%3, stages tile t+2 into (t+2)%3; boundary is
// {vmcnt(4) -> s_barrier -> reads} (counted wait never drains until tail).
// Phase = {ds_read frags -> stage calls -> s_barrier -> lgkmcnt(0)+sched_barrier(0) ->
// setprio(1) -> 16 MFMA -> setprio(0) -> s_barrier}. Swizzle both-sides (0 conflicts),
// serpentine N-super + m204 XCD rank order (FETCH-optimal).
template<int MODE>
__global__ __launch_bounds__(256)
void gemm8ph(const unsigned short* __restrict__ A, const unsigned short* __restrict__ Bt,
             const float* __restrict__ bias, const float* __restrict__ resid,
             void* __restrict__ out, int M, int N, int K, int NSUP) {
    constexpr int BK  = 32;
    constexpr int BM  = 128, BN = 128;
    constexpr int WGN = 2;
    constexpr int WM  = 64, WN = 64;
    constexpr int MT  = 4, NT = 4;
    constexpr int RPC = 64;                            // rows per stage call

    __shared__ unsigned short As[3][BM * BK];
    __shared__ unsigned short Bs[3][BN * BK];
    const int tid = threadIdx.x;
    const int l = tid & 63, wid = tid >> 6;
    const int lr = l & 15, lg = l >> 4;
    const int wr = wid / WGN, wc = wid % WGN;

    const int nN = gridDim.x, nM = gridDim.y;
    const int nTot = nN * nM;
    const int orig = blockIdx.x + nN * blockIdx.y;
    const int q8 = nTot >> 3, r8 = nTot & 7;
    const int xcd = orig & 7, idx = orig >> 3;
    const int rank = (xcd < r8 ? xcd * (q8 + 1) : r8 * (q8 + 1) + (xcd - r8) * q8) + idx;
    const int fullg = nM * NSUP;
    const int sup = rank / fullg;
    const int rem = rank - sup * fullg;
    const int n0s = sup * NSUP;
    int wsup = nN - n0s; if (wsup > NSUP) wsup = NSUP;
    const int mloc = rem / wsup;
    const int nloc = rem - mloc * wsup;
    const int bm0 = mloc * BM;
    const int bn0 = (n0s + nloc) * BN;

    const int srow = wid * 16 + (l >> 2);
    const int slb  = (l & 3) ^ ((l >> 3) & 3);
    auto stageHalf = [&](int ring, int kt, int half) {
        const int k0 = kt * BK;
        if (half == 0) {
#pragma unroll
            for (int c = 0; c < BM / RPC; ++c) {
                int gr = bm0 + c * RPC + srow; gr = gr < M ? gr : M - 1;
                g2l16(A + (size_t)gr * K + k0 + slb * 8, &As[ring][(c * RPC + wid * 16) * BK]);
            }
        } else {
#pragma unroll
            for (int c = 0; c < BN / RPC; ++c) {
                int gr = bn0 + c * RPC + srow;
                g2l16(Bt + (size_t)gr * K + k0 + slb * 8, &Bs[ring][(c * RPC + wid * 16) * BK]);
            }
        }
    };

    f32x4 acc[MT][NT];
#pragma unroll
    for (int i = 0; i < MT; ++i)
#pragma unroll
        for (int j = 0; j < NT; ++j) acc[i][j] = (f32x4){0.f, 0.f, 0.f, 0.f};

    const int NK = K / BK;
    stageHalf(0, 0, 0); stageHalf(0, 0, 1);
    stageHalf(1, 1, 0); stageHalf(1, 1, 1);

    const int rxor = (lr >> 1) & 3;
    int ring = 0;
    for (int kt = 0; kt < NK; ++kt) {
        if (kt + 1 < NK) { asm volatile("s_waitcnt vmcnt(4)" ::: "memory"); }
        else             { asm volatile("s_waitcnt vmcnt(0)" ::: "memory"); }
        __builtin_amdgcn_s_barrier();
        __builtin_amdgcn_sched_barrier(0);
        const unsigned short* Ab = &As[ring][0];
        const unsigned short* Bb = &Bs[ring][0];
        const int rnext = ring >= 1 ? ring - 1 : 2;
        const bool st = (kt + 2 < NK);

        short8 bfr[NT];
#pragma unroll
        for (int nt = 0; nt < NT; ++nt)
            bfr[nt] = *(const short8*)&Bb[(wc * WN + nt * 16 + lr) * BK + ((lg ^ rxor) * 8)];
        short8 af[4];
#pragma unroll
        for (int mt = 0; mt < 4; ++mt)
            af[mt] = *(const short8*)&Ab[(wr * WM + mt * 16 + lr) * BK + ((lg ^ rxor) * 8)];
        if (st) { stageHalf(rnext, kt + 2, 0); stageHalf(rnext, kt + 2, 1); }
        __builtin_amdgcn_s_barrier();
        asm volatile("s_waitcnt lgkmcnt(0)" ::: "memory");
        __builtin_amdgcn_sched_barrier(0);
        __builtin_amdgcn_s_setprio(1);
#pragma unroll
        for (int mt = 0; mt < 4; ++mt)
#pragma unroll
            for (int nt = 0; nt < NT; ++nt)
                acc[mt][nt] = __builtin_amdgcn_mfma_f32_16x16x32_bf16(
                    af[mt], bfr[nt], acc[mt][nt], 0, 0, 0);
        __builtin_amdgcn_s_setprio(0);
        __builtin_amdgcn_s_barrier();
        ring = ring < 2 ? ring + 1 : 0;
    }

#pragma unroll
    for (int mt = 0; mt < MT; ++mt)
#pragma unroll
        for (int nt = 0; nt < NT; ++nt)
#pragma unroll
            for (int r = 0; r < 4; ++r) {
                int gm = bm0 + wr * WM + mt * 16 + lg * 4 + r;
                int gn = bn0 + wc * WN + nt * 16 + lr;
                if (gm < M) {
                    float c = acc[mt][nt][r] + bias[gn];
                    if (MODE == 0) {
                        if (gn < 768) c *= 0.125f;
                        ((unsigned short*)out)[(size_t)gm * N + gn] = f2bf(c);
                    } else if (MODE == 1) {
                        ((float*)out)[(size_t)gm * N + gn] = c + resid[(size_t)gm * N + gn];
                    } else {
                        ((unsigned short*)out)[(size_t)gm * N + gn] = f2bf(gelu_f(c));
                    }
                }
            }
}

// ---------------- MFMA attention: one block per (b,h), 4 waves ----------------
__global__ __launch_bounds__(256)
void attn_mfma(const unsigned short* __restrict__ qkv, const int* __restrict__ mask,
               unsigned short* __restrict__ ctx) {
    __shared__ unsigned short Ks[208 * 64];
    __shared__ unsigned short Vt[64 * 256];
    __shared__ unsigned short Psl[4][16 * 40];
    __shared__ float maskadj[224];
    const int bh = blockIdx.x, b = bh / 12, h = bh - b * 12;
    const int tid = threadIdx.x, l = tid & 63, w = tid >> 6;
    const int lr = l & 15, lg = l >> 4;
    const unsigned short* Qg = qkv + (size_t)b * 197 * 2304 + h * 64;
    const unsigned short* Kg = Qg + 768;
    const unsigned short* Vg = Qg + 1536;

    if (tid < 224)
        maskadj[tid] = tid < 197 ? -10000.f * (1.f - (float)mask[b * 197 + tid]) : -1e30f;

    for (int c = w; c < 26; c += 4) {
        int row = c * 8 + (l >> 3);
        int rc = row < 197 ? row : 196;
        int blk = (l & 7) ^ (row & 7);
        g2l16(Kg + (size_t)rc * 2304 + blk * 8, &Ks[c * 8 * 64]);
    }
    {
        int jj = tid >> 3, db = tid & 7;
#pragma unroll
        for (int it = 0; it < 7; ++it) {
            int j = it * 32 + jj;
            short8 v = (short8){0, 0, 0, 0, 0, 0, 0, 0};
            if (j < 197) v = *(const short8*)(Vg + (size_t)j * 2304 + db * 8);
#pragma unroll
            for (int e = 0; e < 8; ++e) {
                int d = db * 8 + e;
                Vt[d * 256 + (((j >> 3) ^ (d & 7)) * 8) + (j & 7)] = (unsigned short)v[e];
            }
        }
    }
    __syncthreads();

    for (int t = w; t < 13; t += 4) {
        const int q0 = t * 16;
        int qr = q0 + lr; qr = qr < 197 ? qr : 196;
        const short8 qf0 = *(const short8*)(Qg + (size_t)qr * 2304 + lg * 8);
        const short8 qf1 = *(const short8*)(Qg + (size_t)qr * 2304 + 32 + lg * 8);

        f32x4 sc[13];
#pragma unroll
        for (int kt = 0; kt < 13; ++kt) {
            const int krow = kt * 16 + lr;
            const short8 kf0 = *(const short8*)&Ks[krow * 64 + ((lg ^ (lr & 7)) * 8)];
            const short8 kf1 = *(const short8*)&Ks[krow * 64 + (((4 + lg) ^ (lr & 7)) * 8)];
            f32x4 a = (f32x4){0.f, 0.f, 0.f, 0.f};
            a = __builtin_amdgcn_mfma_f32_16x16x32_bf16(qf0, kf0, a, 0, 0, 0);
            a = __builtin_amdgcn_mfma_f32_16x16x32_bf16(qf1, kf1, a, 0, 0, 0);
            sc[kt] = a;
        }
        float mx[4] = {-1e30f, -1e30f, -1e30f, -1e30f};
#pragma unroll
        for (int kt = 0; kt < 13; ++kt) {
            float ma = maskadj[kt * 16 + lr];
#pragma unroll
            for (int r = 0; r < 4; ++r) {
                sc[kt][r] += ma;
                mx[r] = fmaxf(mx[r], sc[kt][r]);
            }
        }
#pragma unroll
        for (int r = 0; r < 4; ++r) {
            mx[r] = fmaxf(mx[r], __shfl_xor(mx[r], 1));
            mx[r] = fmaxf(mx[r], __shfl_xor(mx[r], 2));
            mx[r] = fmaxf(mx[r], __shfl_xor(mx[r], 4));
            mx[r] = fmaxf(mx[r], __shfl_xor(mx[r], 8));
        }
        float sm[4] = {0.f, 0.f, 0.f, 0.f};
#pragma unroll
        for (int kt = 0; kt < 13; ++kt)
#pragma unroll
            for (int r = 0; r < 4; ++r) {
                float p = __expf(sc[kt][r] - mx[r]);
                sc[kt][r] = p;
                sm[r] += p;
            }
#pragma unroll
        for (int r = 0; r < 4; ++r) {
            sm[r] += __shfl_xor(sm[r], 1);
            sm[r] += __shfl_xor(sm[r], 2);
            sm[r] += __shfl_xor(sm[r], 4);
            sm[r] += __shfl_xor(sm[r], 8);
            sm[r] = 1.f / sm[r];
        }
        f32x4 ao[4];
#pragma unroll
        for (int dt = 0; dt < 4; ++dt) ao[dt] = (f32x4){0.f, 0.f, 0.f, 0.f};
        unsigned short* Pw = &Psl[w][0];
#pragma unroll
        for (int ks = 0; ks < 7; ++ks) {
#pragma unroll
            for (int tl = 0; tl < 2; ++tl) {
                const int kt = ks * 2 + tl;
#pragma unroll
                for (int r = 0; r < 4; ++r) {
                    unsigned short pv = 0;
                    if (kt < 13) pv = f2bf(sc[kt][r] * sm[r]);
                    Pw[(lg * 4 + r) * 40 + tl * 16 + lr] = pv;
                }
            }
            const short8 pf = *(const short8*)&Pw[lr * 40 + lg * 8];
#pragma unroll
            for (int dt = 0; dt < 4; ++dt) {
                const int drow = dt * 16 + lr;
                const short8 vf = *(const short8*)&Vt[drow * 256 + (((4 * ks + lg) ^ (lr & 7)) * 8)];
                ao[dt] = __builtin_amdgcn_mfma_f32_16x16x32_bf16(vf, pf, ao[dt], 0, 0, 0);
            }
        }
        const int q = q0 + lr;
        if (q < 197) {
            unsigned short* crow = ctx + ((size_t)b * 197 + q) * 768 + h * 64;
#pragma unroll
            for (int dt = 0; dt < 4; ++dt) {
                union { unsigned short u[4]; uint2 v; } pk;
#pragma unroll
                for (int r = 0; r < 4; ++r) pk.u[r] = f2bf(ao[dt][r]);
                *(uint2*)(crow + dt * 16 + lg * 4) = pk.v;
            }
        }
    }
}

extern "C" void kernel_launch(void* const* d_in, const int* in_sizes, int n_in,
                              void* d_out, int out_size, void* d_ws, size_t ws_size,
                              hipStream_t stream) {
    const float* x    = (const float*)d_in[0];
    const float* Wq   = (const float*)d_in[1];
    const float* bq   = (const float*)d_in[2];
    const float* Wk   = (const float*)d_in[3];
    const float* bk   = (const float*)d_in[4];
    const float* Wv   = (const float*)d_in[5];
    const float* bv   = (const float*)d_in[6];
    const float* Wo   = (const float*)d_in[7];
    const float* bo   = (const float*)d_in[8];
    const float* ln1w = (const float*)d_in[9];
    const float* ln1b = (const float*)d_in[10];
    const float* W1   = (const float*)d_in[11];
    const float* b1   = (const float*)d_in[12];
    const float* W2   = (const float*)d_in[13];
    const float* b2   = (const float*)d_in[14];
    const float* ln2w = (const float*)d_in[15];
    const float* ln2b = (const float*)d_in[16];
    const int*   mask = (const int*)d_in[17];

    size_t off = 0;
    auto nxt = [&](size_t bytes) -> void* {
        void* r = (char*)d_ws + off; off += (bytes + 255) & ~(size_t)255; return r;
    };
    unsigned short* hbuf  = (unsigned short*)nxt((size_t)BS_ * 768 * 2);
    unsigned short* qkvg  = (unsigned short*)nxt((size_t)BS_ * 3072 * 2);  // QKV (2304), reused for FFN1 out (3072)
    unsigned short* wqkvT = (unsigned short*)nxt((size_t)2304 * 768 * 2);
    unsigned short* woT   = (unsigned short*)nxt((size_t)768 * 768 * 2);
    unsigned short* w1T   = (unsigned short*)nxt((size_t)3072 * 768 * 2);
    unsigned short* w2T   = (unsigned short*)nxt((size_t)768 * 3072 * 2);
    float*          bcat  = (float*)nxt(2304 * 4);
    unsigned short* ctx   = (unsigned short*)nxt((size_t)BS_ * 768 * 2);
    (void)ws_size; (void)in_sizes; (void)n_in; (void)out_size;

    // prep: weight transposes + bias concat + LN1 overlapped in one dispatch
    prep_kernel<<<6913 + BS_, 256, 0, stream>>>(Wq, Wk, Wv, Wo, W1, W2, bq, bk, bv,
                                                x, ln1w, ln1b,
                                                wqkvT, woT, w1T, w2T, bcat, hbuf);
    // QKV: 1782 blocks (R18-verified)
    gemm8ph<0><<<dim3(18, 99), 256, 0, stream>>>(hbuf, wqkvT, bcat, nullptr, qkvg, BS_, 2304, 768, 9);
    attn_mfma<<<768, 256, 0, stream>>>(qkvg, mask, ctx);
    // O-proj: 594 blocks, NSUP=6 (whole B 1.2MB resident)
    gemm8ph<1><<<dim3(6, 99), 256, 0, stream>>>(ctx, woT, bo, x, d_out, BS_, 768, 768, 6);
    ln_kernel<<<BS_, 256, 0, stream>>>((const float*)d_out, ln2w, ln2b, hbuf);
    // FFN1: 2376 blocks (R19-verified: 130.8us)
    gemm8ph<2><<<dim3(24, 99), 256, 0, stream>>>(hbuf, w1T, b1, nullptr, qkvg, BS_, 3072, 768, 12);
    // FFN2: K=3072, 594 blocks, NSUP=3 (B-super 2.4MB)
    gemm8ph<1><<<dim3(6, 99), 256, 0, stream>>>(qkvg, w2T, b2, (const float*)d_out, d_out, BS_, 768, 3072, 3);
}